// Round 8
// baseline (190.977 us; speedup 1.0000x reference)
//
#include <hip/hip_runtime.h>
#include <cstdint>
#include <cstddef>

// Problem: B=8,S=2048,E=512,FFN=2048,Q=8 -> M=16384, K=2048, N=512.
// Round-8: identical to round 7 EXCEPT __launch_bounds__(512, 2).
// R7's (512,4) was interpreted as 4 blocks/CU -> 64-VGPR cap -> scratch
// spills (FETCH +5MB, WRITE +9MB) which poisoned the 4-waves/SIMD test.
// (512,2) caps at 128 VGPR (2 blk x 8 waves = 16 waves/CU = 4/SIMD).
// BM=64, BN=256, 512 thr = 8 waves (wave-tile 32x64), grid=512 -> 2 blocks/CU.
// Conflict-free LDS images, one barrier/K-step, counted vmcnt(6).

typedef __attribute__((ext_vector_type(8))) short s16x8;
typedef __attribute__((ext_vector_type(4))) float f32x4;

__device__ __forceinline__ unsigned short f2bf(float f) {
  unsigned int u = __float_as_uint(f);
  unsigned int r = u + 0x7fffu + ((u >> 16) & 1u);
  return (unsigned short)(r >> 16);
}

__device__ __forceinline__ void async_copy16(const void* g, void* l) {
  __builtin_amdgcn_global_load_lds(
      (const __attribute__((address_space(1))) void*)(uintptr_t)g,
      (__attribute__((address_space(3))) void*)(unsigned int)(uintptr_t)l,
      16, 0, 0);
}

// ---------------------------------------------------------------------------
// Kernel 1: build w2b image. Layout: [nt(2)][slice s(64)][chunk ci(1024)]x16B,
// ci = nhi*64 + quad*16 + nlo; data = bf16(w2[n][s*32+quad*8 .. +7]).
// ---------------------------------------------------------------------------
__global__ __launch_bounds__(256) void k_w2(const float* __restrict__ w2,
                                            unsigned short* __restrict__ img) {
  const int n = blockIdx.x;   // 0..511
  const int t = threadIdx.x;
  const int s = t >> 2, quad = t & 3;
  const float* src = w2 + (size_t)n * 2048 + t * 8;  // coalesced read
  float4 a = *(const float4*)src;
  float4 b = *(const float4*)(src + 4);
  uint4 pk;
  pk.x = f2bf(a.x) | ((unsigned)f2bf(a.y) << 16);
  pk.y = f2bf(a.z) | ((unsigned)f2bf(a.w) << 16);
  pk.z = f2bf(b.x) | ((unsigned)f2bf(b.y) << 16);
  pk.w = f2bf(b.z) | ((unsigned)f2bf(b.w) << 16);
  const int nt = n >> 8, nl = n & 255, nhi = nl >> 4, nlo = nl & 15;
  const size_t ci = (size_t)(nt * 64 + s) * 1024 + nhi * 64 + quad * 16 + nlo;
  *(uint4*)(img + ci * 8) = pk;
}

// ---------------------------------------------------------------------------
// Kernel 2 (fused): C[m][n] = sum_k relu(z[m]·w1[k]+b1[k]) * w2[n][k] + b2[n]
// ---------------------------------------------------------------------------
__global__ __launch_bounds__(512, 2) void k_fused(
    const float* __restrict__ x, const float* __restrict__ ry,
    const float* __restrict__ w1, const float* __restrict__ b1,
    const unsigned short* __restrict__ w2b, const float* __restrict__ b2,
    float* __restrict__ C) {
  __shared__ unsigned short As[2][64 * 32];   // 2 x 4 KB  XOR-swizzled image
  __shared__ unsigned short Bs[3][256 * 32];  // 3 x 16 KB linear-frag image
  __shared__ float b1s[2048];                 // 8 KB -> 64 KB total

  const int t = threadIdx.x;  // 0..511
  const int lane = t & 63;
  const int w = t >> 6;  // wave 0..7: wm=(w>>2)*32, wn=(w&3)*64
  const int mt = (int)(blockIdx.x >> 1);
  const int nt = (int)(blockIdx.x & 1);
  const int r0 = mt * 64;
  const int c0 = nt * 256;
  const int fp = t & 15;  // f-pair index within the 32-wide K-step
  const int rw = t >> 4;  // 0..31: rows rw*2, rw*2+1

  // ---- prologue part 1: z for this thread's 2 rows (x loads retire now) ----
  float zr[2][8];
  {
    float4 ra = *(const float4*)ry;
    float4 rb = *(const float4*)(ry + 4);
    float cy[8] = {__cosf(ra.x), __cosf(ra.y), __cosf(ra.z), __cosf(ra.w),
                   __cosf(rb.x), __cosf(rb.y), __cosf(rb.z), __cosf(rb.w)};
#pragma unroll
    for (int r = 0; r < 2; ++r) {
      const float* xr = x + (size_t)(r0 + rw * 2 + r) * 512;
      float4 x0 = *(const float4*)xr;
      float4 x1 = *(const float4*)(xr + 4);
      zr[r][0] = __cosf(x0.x) * cy[0];
      zr[r][1] = __cosf(x0.y) * cy[1];
      zr[r][2] = __cosf(x0.z) * cy[2];
      zr[r][3] = __cosf(x0.w) * cy[3];
      zr[r][4] = __cosf(x1.x) * cy[4];
      zr[r][5] = __cosf(x1.y) * cy[5];
      zr[r][6] = __cosf(x1.z) * cy[6];
      zr[r][7] = __cosf(x1.w) * cy[7];
    }
  }
  __builtin_amdgcn_sched_barrier(0);

  // ---- prologue part 2: queue = [b1s(1), st0(2), w1_0(4), st1(2), w1_1(4)]
  const unsigned short* gB = w2b + (size_t)nt * 524288 + t * 8;
  char* lB = (char*)Bs + t * 16;
  auto stage = [&](int s, int buf) {  // 2 chunks/thread (1024 total = 16 KB)
    async_copy16(gB + (size_t)s * 8192, lB + buf * 16384);
    async_copy16(gB + (size_t)s * 8192 + 4096, lB + buf * 16384 + 8192);
  };
  async_copy16(b1 + (size_t)t * 4, (char*)b1s + (size_t)t * 16);
  stage(0, 0);
  f32x4 wA0, wA1, wA2, wA3, wB0, wB1, wB2, wB3;
  {
    const f32x4* p0 = (const f32x4*)(w1 + fp * 16);  // slice 0
    wA0 = p0[0]; wA1 = p0[1]; wA2 = p0[2]; wA3 = p0[3];
  }
  stage(1, 1);
  {
    const f32x4* p1 = (const f32x4*)(w1 + 256 + fp * 16);  // slice 1
    wB0 = p1[0]; wB1 = p1[1]; wB2 = p1[2]; wB3 = p1[3];
  }

  // drain b1s + st0 + w1_0; keep {st1, w1_1} = 6 in flight
  asm volatile("s_waitcnt vmcnt(6) lgkmcnt(0)" ::: "memory");
  __builtin_amdgcn_sched_barrier(0);
  __builtin_amdgcn_s_barrier();

  // ---- act: thread (rw,fp) -> rows rw*2..+1, k-pair fp, XOR image ----
  const int koct = fp >> 2, fpl = fp & 3;
  const int s_off = ((koct ^ (rw & 3)) << 4) + fpl * 4;  // (row>>1)&3 == rw&3
  char* aswr = (char*)As + rw * 128 + s_off;

  auto act = [&](int s, int buf, const f32x4& v0, const f32x4& v1,
                 const f32x4& v2, const f32x4& v3) {
    const float bb0 = b1s[s * 32 + fp * 2];
    const float bb1 = b1s[s * 32 + fp * 2 + 1];
    unsigned int u0, u1;
#define ACT_ROW(R, UD)                                                      \
  {                                                                         \
    float h0 = bb0, h1 = bb1;                                               \
    h0 += zr[R][0] * v0[0]; h1 += zr[R][0] * v2[0];                         \
    h0 += zr[R][1] * v0[1]; h1 += zr[R][1] * v2[1];                         \
    h0 += zr[R][2] * v0[2]; h1 += zr[R][2] * v2[2];                         \
    h0 += zr[R][3] * v0[3]; h1 += zr[R][3] * v2[3];                         \
    h0 += zr[R][4] * v1[0]; h1 += zr[R][4] * v3[0];                         \
    h0 += zr[R][5] * v1[1]; h1 += zr[R][5] * v3[1];                         \
    h0 += zr[R][6] * v1[2]; h1 += zr[R][6] * v3[2];                         \
    h0 += zr[R][7] * v1[3]; h1 += zr[R][7] * v3[3];                         \
    h0 = fmaxf(h0, 0.0f);                                                   \
    h1 = fmaxf(h1, 0.0f);                                                   \
    asm("v_cvt_pk_bf16_f32 %0, %1, %2" : "=v"(UD) : "v"(h0), "v"(h1));      \
  }
    ACT_ROW(0, u0) ACT_ROW(1, u1)
#undef ACT_ROW
    char* dst = aswr + buf * 4096;
    *(unsigned int*)(dst) = u0;       // row rw*2
    *(unsigned int*)(dst + 64) = u1;  // row rw*2+1
  };

  act(0, 0, wA0, wA1, wA2, wA3);  // As[0] (published by body-0's barrier)

  // frag pointers. A: row = wm+i*16+fr (XOR const in i); B: linear image.
  const int wm = (w >> 2) * 32;
  const int wn = (w & 3) * 64;
  const int fr = lane & 15;
  const int quad = lane >> 4;
  const char* pAb = (const char*)As + wm * 64 + fr * 64 +
                    ((quad ^ ((fr >> 1) & 3)) << 4);
  const char* pBb = (const char*)Bs + (w & 3) * 4096 + quad * 256 + fr * 16;

  f32x4 acc[2][4];
#pragma unroll
  for (int i = 0; i < 2; ++i)
#pragma unroll
    for (int j = 0; j < 4; ++j) acc[i][j] = (f32x4){0.f, 0.f, 0.f, 0.f};

// One barrier per K-step. Steady vmcnt(6) keeps {stage(kt+1), w1(kt+1)}.
#define BODY(KT, BUF, BUF2, L0, L1, L2, L3, U0, U1, U2, U3, PRE, ACTG, VMC) \
  {                                                                         \
    asm volatile("s_waitcnt vmcnt(" VMC ") lgkmcnt(0)" ::: "memory");       \
    __builtin_amdgcn_sched_barrier(0);                                      \
    __builtin_amdgcn_s_barrier();                                           \
    if (PRE) {                                                              \
      stage((KT) + 2, BUF2);                                                \
      const f32x4* wp =                                                     \
          (const f32x4*)(w1 + (size_t)((KT) + 2) * 256 + fp * 16);          \
      L0 = wp[0]; L1 = wp[1]; L2 = wp[2]; L3 = wp[3];                       \
    }                                                                       \
    s16x8 af[2], bfv[4];                                                    \
    {                                                                       \
      const char* pA = pAb + ((KT) & 1) * 4096;                             \
      const char* pB = pBb + (BUF) * 16384;                                 \
      af[0] = *(const s16x8*)(pA);                                          \
      af[1] = *(const s16x8*)(pA + 1024);                                   \
      bfv[0] = *(const s16x8*)(pB);                                         \
      bfv[1] = *(const s16x8*)(pB + 1024);                                  \
      bfv[2] = *(const s16x8*)(pB + 2048);                                  \
      bfv[3] = *(const s16x8*)(pB + 3072);                                  \
    }                                                                       \
    if (ACTG) act((KT) + 1, ((KT) + 1) & 1, U0, U1, U2, U3);                \
    __builtin_amdgcn_s_setprio(1);                                          \
    _Pragma("unroll") for (int i = 0; i < 2; ++i)                           \
        _Pragma("unroll") for (int j = 0; j < 4; ++j) acc[i][j] =           \
        __builtin_amdgcn_mfma_f32_16x16x32_bf16(af[i], bfv[j], acc[i][j],   \
                                                0, 0, 0);                   \
    __builtin_amdgcn_s_setprio(0);                                          \
  }

  for (int kt = 0; kt < 60; kt += 6) {
    BODY(kt + 0, 0, 2, wA0, wA1, wA2, wA3, wB0, wB1, wB2, wB3, true, true, "6");
    BODY(kt + 1, 1, 0, wB0, wB1, wB2, wB3, wA0, wA1, wA2, wA3, true, true, "6");
    BODY(kt + 2, 2, 1, wA0, wA1, wA2, wA3, wB0, wB1, wB2, wB3, true, true, "6");
    BODY(kt + 3, 0, 2, wB0, wB1, wB2, wB3, wA0, wA1, wA2, wA3, true, true, "6");
    BODY(kt + 4, 1, 0, wA0, wA1, wA2, wA3, wB0, wB1, wB2, wB3, true, true, "6");
    BODY(kt + 5, 2, 1, wB0, wB1, wB2, wB3, wA0, wA1, wA2, wA3, true, true, "6");
  }
  // tail: 60 (stage 62), 61 (stage 63), 62 (act 63 only), 63 (MFMA only)
  BODY(60, 0, 2, wA0, wA1, wA2, wA3, wB0, wB1, wB2, wB3, true, true, "6");
  BODY(61, 1, 0, wB0, wB1, wB2, wB3, wA0, wA1, wA2, wA3, true, true, "6");
  BODY(62, 2, 1, wA0, wA1, wA2, wA3, wB0, wB1, wB2, wB3, false, true, "6");
  BODY(63, 0, 2, wB0, wB1, wB2, wB3, wA0, wA1, wA2, wA3, false, false, "0");
#undef BODY

  // epilogue: C/D layout col = lane&15, row = quad*4 + reg (m89/m91 verified)
  float bias[4];
#pragma unroll
  for (int j = 0; j < 4; ++j) bias[j] = b2[c0 + wn + j * 16 + fr];
#pragma unroll
  for (int i = 0; i < 2; ++i) {
    const int rbase = r0 + wm + i * 16 + quad * 4;
#pragma unroll
    for (int rr = 0; rr < 4; ++rr) {
      float* crow = C + (size_t)(rbase + rr) * 512;
#pragma unroll
      for (int j = 0; j < 4; ++j)
        crow[c0 + wn + j * 16 + fr] = acc[i][j][rr] + bias[j];
    }
  }
}

// ---------------------------------------------------------------------------
// Emergency fallback (only if ws_size is tiny): fully fused fp32, 1 row/block.
// ---------------------------------------------------------------------------
__global__ __launch_bounds__(256) void k_naive(
    const float* __restrict__ x, const float* __restrict__ ry,
    const float* __restrict__ w1, const float* __restrict__ b1,
    const float* __restrict__ w2, const float* __restrict__ b2,
    float* __restrict__ out) {
  __shared__ float zsh[8];
  __shared__ float acts[2048];
  const int r = blockIdx.x;
  const int t = threadIdx.x;
  if (t < 8) zsh[t] = __cosf(x[(size_t)r * 512 + t]) * __cosf(ry[t]);
  __syncthreads();
  float z[8];
#pragma unroll
  for (int q = 0; q < 8; ++q) z[q] = zsh[q];
#pragma unroll
  for (int i = 0; i < 8; ++i) {
    const int f = t * 8 + i;
    const float* wr = w1 + (size_t)f * 8;
    float4 a = *(const float4*)wr;
    float4 b = *(const float4*)(wr + 4);
    float h = b1[f] + z[0] * a.x + z[1] * a.y + z[2] * a.z + z[3] * a.w +
              z[4] * b.x + z[5] * b.y + z[6] * b.z + z[7] * b.w;
    acts[f] = fmaxf(h, 0.0f);
  }
  __syncthreads();
  for (int ee = 0; ee < 2; ++ee) {
    const int e = t + ee * 256;
    const float* wr = w2 + (size_t)e * 2048;
    float acc = b2[e];
    for (int f = 0; f < 2048; f += 4) {
      float4 wv = *(const float4*)(wr + f);
      float4 av = *(const float4*)(acts + f);
      acc += av.x * wv.x + av.y * wv.y + av.z * wv.z + av.w * wv.w;
    }
    out[(size_t)r * 512 + e] = acc;
  }
}

extern "C" void kernel_launch(void* const* d_in, const int* in_sizes, int n_in,
                              void* d_out, int out_size, void* d_ws,
                              size_t ws_size, hipStream_t stream) {
  const float* x  = (const float*)d_in[0];
  const float* ry = (const float*)d_in[1];
  const float* w1 = (const float*)d_in[2];
  const float* b1 = (const float*)d_in[3];
  const float* w2 = (const float*)d_in[4];
  const float* b2 = (const float*)d_in[5];
  float* out = (float*)d_out;

  const size_t w2b_bytes = (size_t)512 * 2048 * 2;  // 2 MB bf16 w2 image
  if (ws_size < w2b_bytes) {
    k_naive<<<dim3(16384), dim3(256), 0, stream>>>(x, ry, w1, b1, w2, b2, out);
    return;
  }
  unsigned short* w2b = (unsigned short*)d_ws;
  k_w2<<<dim3(512), dim3(256), 0, stream>>>(w2, w2b);
  k_fused<<<dim3(512), dim3(512), 0, stream>>>(x, ry, w1, b1, w2b, b2, out);
}

// Round 9
// 138.793 us; speedup vs baseline: 1.3760x; 1.3760x over previous
//
#include <hip/hip_runtime.h>
#include <cstdint>
#include <cstddef>

// Problem: B=8,S=2048,E=512,FFN=2048,Q=8 -> M=16384, K=2048, N=512.
// Round-9: R6 shape (BM=64, BN=256, 256 thr, 4 waves, 64x64 wave tiles,
// grid=512, 2 blocks/CU) but B-fragments are loaded DIRECTLY global->VGPR
// from the w2b image (zero intra-block reuse => LDS staging of B was pure
// overhead; w2b is 2 MB = L2-resident). LDS = As[2] (XOR image) + b1s only
// (16 KB). One barrier per K-step; counted vmcnt(8) = {B(kt+1), w1(kt+2)}.

typedef __attribute__((ext_vector_type(8))) short s16x8;
typedef __attribute__((ext_vector_type(4))) float f32x4;

__device__ __forceinline__ unsigned short f2bf(float f) {
  unsigned int u = __float_as_uint(f);
  unsigned int r = u + 0x7fffu + ((u >> 16) & 1u);
  return (unsigned short)(r >> 16);
}

__device__ __forceinline__ void async_copy16(const void* g, void* l) {
  __builtin_amdgcn_global_load_lds(
      (const __attribute__((address_space(1))) void*)(uintptr_t)g,
      (__attribute__((address_space(3))) void*)(unsigned int)(uintptr_t)l,
      16, 0, 0);
}

// ---------------------------------------------------------------------------
// Kernel 1: build w2b image. chunk ci = (nt*64+s)*1024 + nhi*64 + quad*16 +
// nlo; data = bf16(w2[n][s*32+quad*8 .. +7]). A wave's B-frag j at slice s is
// then 64 contiguous chunks (1 KB coalesced burst) starting at
// (nt*64+s)*1024 + (w*4+j)*64.
// ---------------------------------------------------------------------------
__global__ __launch_bounds__(256) void k_w2(const float* __restrict__ w2,
                                            unsigned short* __restrict__ img) {
  const int n = blockIdx.x;   // 0..511
  const int t = threadIdx.x;
  const int s = t >> 2, quad = t & 3;
  const float* src = w2 + (size_t)n * 2048 + t * 8;  // coalesced read
  float4 a = *(const float4*)src;
  float4 b = *(const float4*)(src + 4);
  uint4 pk;
  pk.x = f2bf(a.x) | ((unsigned)f2bf(a.y) << 16);
  pk.y = f2bf(a.z) | ((unsigned)f2bf(a.w) << 16);
  pk.z = f2bf(b.x) | ((unsigned)f2bf(b.y) << 16);
  pk.w = f2bf(b.z) | ((unsigned)f2bf(b.w) << 16);
  const int nt = n >> 8, nl = n & 255, nhi = nl >> 4, nlo = nl & 15;
  const size_t ci = (size_t)(nt * 64 + s) * 1024 + nhi * 64 + quad * 16 + nlo;
  *(uint4*)(img + ci * 8) = pk;
}

// ---------------------------------------------------------------------------
// Kernel 2 (fused): C[m][n] = sum_k relu(z[m]·w1[k]+b1[k]) * w2[n][k] + b2[n]
// ---------------------------------------------------------------------------
__global__ __launch_bounds__(256, 2) void k_fused(
    const float* __restrict__ x, const float* __restrict__ ry,
    const float* __restrict__ w1, const float* __restrict__ b1,
    const unsigned short* __restrict__ w2b, const float* __restrict__ b2,
    float* __restrict__ C) {
  __shared__ unsigned short As[2][64 * 32];  // 2 x 4 KB XOR-swizzled image
  __shared__ float b1s[2048];                // 8 KB -> 16 KB total

  const int t = threadIdx.x;  // 0..255
  const int lane = t & 63;
  const int w = t >> 6;  // wave 0..3 -> wn = w*64
  const int mt = (int)(blockIdx.x >> 1);
  const int nt = (int)(blockIdx.x & 1);
  const int r0 = mt * 64;
  const int c0 = nt * 256;
  const int fp = t & 15;  // f-pair index within the 32-wide K-step
  const int rq = t >> 4;  // row-quad 0..15: rows rq*4 .. rq*4+3
  const int fr = lane & 15;
  const int quad = lane >> 4;

  // ---- z for this thread's 4 rows (plain loads, retire in prologue) ----
  float zr[4][8];
  {
    float4 ra = *(const float4*)ry;
    float4 rb = *(const float4*)(ry + 4);
    float cy[8] = {__cosf(ra.x), __cosf(ra.y), __cosf(ra.z), __cosf(ra.w),
                   __cosf(rb.x), __cosf(rb.y), __cosf(rb.z), __cosf(rb.w)};
#pragma unroll
    for (int r = 0; r < 4; ++r) {
      const float* xr = x + (size_t)(r0 + rq * 4 + r) * 512;
      float4 x0 = *(const float4*)xr;
      float4 x1 = *(const float4*)(xr + 4);
      zr[r][0] = __cosf(x0.x) * cy[0];
      zr[r][1] = __cosf(x0.y) * cy[1];
      zr[r][2] = __cosf(x0.z) * cy[2];
      zr[r][3] = __cosf(x0.w) * cy[3];
      zr[r][4] = __cosf(x1.x) * cy[4];
      zr[r][5] = __cosf(x1.y) * cy[5];
      zr[r][6] = __cosf(x1.z) * cy[6];
      zr[r][7] = __cosf(x1.w) * cy[7];
    }
  }
  __builtin_amdgcn_sched_barrier(0);

  // ---- B-frag direct-load base: byte addr(s,j) = gBb + s*16384 + j*1024 ----
  const char* gBb =
      (const char*)w2b +
      ((size_t)nt * 64 * 1024 + (size_t)w * 256 + quad * 16 + fr) * 16;
#define LOADB(S, D)                                        \
  {                                                        \
    const char* p_ = gBb + (size_t)(S) * 16384;            \
    D[0] = *(const s16x8*)(p_);                            \
    D[1] = *(const s16x8*)(p_ + 1024);                     \
    D[2] = *(const s16x8*)(p_ + 2048);                     \
    D[3] = *(const s16x8*)(p_ + 3072);                     \
  }

  // ---- prologue: b1s async; B(0)->Bp; w1(0)->wA; w1(1)->wB; drain ----
  async_copy16(b1 + (size_t)t * 4, (char*)b1s + (size_t)t * 16);
  async_copy16(b1 + (size_t)(t + 256) * 4, (char*)b1s + (size_t)(t + 256) * 16);
  s16x8 Bp[4], Bq[4];
  LOADB(0, Bp);
  f32x4 wA0, wA1, wA2, wA3, wB0, wB1, wB2, wB3;
  {
    const f32x4* p0 = (const f32x4*)(w1 + fp * 16);  // slice 0
    wA0 = p0[0]; wA1 = p0[1]; wA2 = p0[2]; wA3 = p0[3];
    const f32x4* p1 = (const f32x4*)(w1 + 256 + fp * 16);  // slice 1
    wB0 = p1[0]; wB1 = p1[1]; wB2 = p1[2]; wB3 = p1[3];
  }
  asm volatile("s_waitcnt vmcnt(0) lgkmcnt(0)" ::: "memory");
  __builtin_amdgcn_sched_barrier(0);
  __builtin_amdgcn_s_barrier();  // b1s visible

  // ---- act: thread (rq,fp) -> rows rq*4..+3, k-pair fp (R6-verified) ----
  const int q0 = rq & 1;
  const int koct = fp >> 2, fpl = fp & 3;
  const int sA_off = ((koct ^ ((rq * 2) & 3)) << 4) + fpl * 4;      // rows 0,1
  const int sB_off = ((koct ^ ((rq * 2 + 1) & 3)) << 4) + fpl * 4;  // rows 2,3
  const int rw0 = ((rq * 4 + 0) ^ q0) * 64;
  const int rw1 = ((rq * 4 + 1) ^ q0) * 64;
  const int rw2 = ((rq * 4 + 2) ^ q0) * 64;
  const int rw3 = ((rq * 4 + 3) ^ q0) * 64;

  auto act = [&](int s, int buf, const f32x4& v0, const f32x4& v1,
                 const f32x4& v2, const f32x4& v3) {
    const float bb0 = b1s[s * 32 + fp * 2];
    const float bb1 = b1s[s * 32 + fp * 2 + 1];
    unsigned int u0, u1, u2, u3;
#define ACT_ROW(R, UD)                                                      \
  {                                                                         \
    float h0 = bb0, h1 = bb1;                                               \
    h0 += zr[R][0] * v0[0]; h1 += zr[R][0] * v2[0];                         \
    h0 += zr[R][1] * v0[1]; h1 += zr[R][1] * v2[1];                         \
    h0 += zr[R][2] * v0[2]; h1 += zr[R][2] * v2[2];                         \
    h0 += zr[R][3] * v0[3]; h1 += zr[R][3] * v2[3];                         \
    h0 += zr[R][4] * v1[0]; h1 += zr[R][4] * v3[0];                         \
    h0 += zr[R][5] * v1[1]; h1 += zr[R][5] * v3[1];                         \
    h0 += zr[R][6] * v1[2]; h1 += zr[R][6] * v3[2];                         \
    h0 += zr[R][7] * v1[3]; h1 += zr[R][7] * v3[3];                         \
    h0 = fmaxf(h0, 0.0f);                                                   \
    h1 = fmaxf(h1, 0.0f);                                                   \
    asm("v_cvt_pk_bf16_f32 %0, %1, %2" : "=v"(UD) : "v"(h0), "v"(h1));      \
  }
    ACT_ROW(0, u0) ACT_ROW(1, u1) ACT_ROW(2, u2) ACT_ROW(3, u3)
#undef ACT_ROW
    char* base = (char*)As + buf * 4096;
    *(unsigned int*)(base + rw0 + sA_off) = q0 ? u1 : u0;
    *(unsigned int*)(base + rw1 + sA_off) = q0 ? u0 : u1;
    *(unsigned int*)(base + rw2 + sB_off) = q0 ? u3 : u2;
    *(unsigned int*)(base + rw3 + sB_off) = q0 ? u2 : u3;
  };

  act(0, 0, wA0, wA1, wA2, wA3);  // As[0]
  asm volatile("s_waitcnt lgkmcnt(0)" ::: "memory");
  __builtin_amdgcn_sched_barrier(0);
  __builtin_amdgcn_s_barrier();  // publish As[0]

  // frag pointer: row = i*16+fr, koct = quad (XOR image; R6-verified)
  const int wn = w * 64;
  const char* pAb =
      (const char*)As + fr * 64 + ((quad ^ ((fr >> 1) & 3)) << 4);

  f32x4 acc[4][4];
#pragma unroll
  for (int i = 0; i < 4; ++i)
#pragma unroll
    for (int j = 0; j < 4; ++j) acc[i][j] = (f32x4){0.f, 0.f, 0.f, 0.f};

// Per iter: issue B(kt+1)->BL, w1(kt+2)->WL; vmcnt(VMC) => B(kt) in BU and
// w1(kt+1) in WU* ready; read af; act(kt+1)->As[nxt]; lgkm(0); MFMA; barrier.
#define BODY(KT, BU, BL, WU0, WU1, WU2, WU3, WL0, WL1, WL2, WL3, BPRE,      \
             WPRE, ACTG, VMC)                                               \
  {                                                                         \
    if (BPRE) LOADB((KT) + 1, BL);                                          \
    if (WPRE) {                                                             \
      const f32x4* wp =                                                     \
          (const f32x4*)(w1 + (size_t)((KT) + 2) * 256 + fp * 16);          \
      WL0 = wp[0]; WL1 = wp[1]; WL2 = wp[2]; WL3 = wp[3];                   \
    }                                                                       \
    asm volatile("s_waitcnt vmcnt(" VMC ")" ::: "memory");                  \
    __builtin_amdgcn_sched_barrier(0);                                      \
    s16x8 af[4];                                                            \
    {                                                                       \
      const char* pA = pAb + ((KT) & 1) * 4096;                             \
      af[0] = *(const s16x8*)(pA);                                          \
      af[1] = *(const s16x8*)(pA + 1024);                                   \
      af[2] = *(const s16x8*)(pA + 2048);                                   \
      af[3] = *(const s16x8*)(pA + 3072);                                   \
    }                                                                       \
    if (ACTG) act((KT) + 1, ((KT) + 1) & 1, WU0, WU1, WU2, WU3);            \
    asm volatile("s_waitcnt lgkmcnt(0)" ::: "memory");                      \
    __builtin_amdgcn_sched_barrier(0);                                      \
    __builtin_amdgcn_s_setprio(1);                                          \
    _Pragma("unroll") for (int i = 0; i < 4; ++i)                           \
        _Pragma("unroll") for (int j = 0; j < 4; ++j) acc[i][j] =           \
        __builtin_amdgcn_mfma_f32_16x16x32_bf16(af[i], BU[j], acc[i][j],    \
                                                0, 0, 0);                   \
    __builtin_amdgcn_s_setprio(0);                                          \
    __builtin_amdgcn_s_barrier();                                           \
  }

  for (int kt = 0; kt < 62; kt += 2) {
    BODY(kt, Bp, Bq, wB0, wB1, wB2, wB3, wA0, wA1, wA2, wA3, true, true,
         true, "8");
    BODY(kt + 1, Bq, Bp, wA0, wA1, wA2, wA3, wB0, wB1, wB2, wB3, true, true,
         true, "8");
  }
  // tail: 62 (load B63, act 63), 63 (MFMA only)
  BODY(62, Bp, Bq, wB0, wB1, wB2, wB3, wA0, wA1, wA2, wA3, true, false, true,
       "4");
  BODY(63, Bq, Bp, wA0, wA1, wA2, wA3, wB0, wB1, wB2, wB3, false, false,
       false, "0");
#undef BODY
#undef LOADB

  // epilogue: C/D layout col = lane&15, row = quad*4 + reg (m89/m91 verified)
  float bias[4];
#pragma unroll
  for (int j = 0; j < 4; ++j) bias[j] = b2[c0 + wn + j * 16 + fr];
#pragma unroll
  for (int i = 0; i < 4; ++i) {
    const int rbase = r0 + i * 16 + quad * 4;
#pragma unroll
    for (int rr = 0; rr < 4; ++rr) {
      float* crow = C + (size_t)(rbase + rr) * 512;
#pragma unroll
      for (int j = 0; j < 4; ++j)
        crow[c0 + wn + j * 16 + fr] = acc[i][j][rr] + bias[j];
    }
  }
}

// ---------------------------------------------------------------------------
// Emergency fallback (only if ws_size is tiny): fully fused fp32, 1 row/block.
// ---------------------------------------------------------------------------
__global__ __launch_bounds__(256) void k_naive(
    const float* __restrict__ x, const float* __restrict__ ry,
    const float* __restrict__ w1, const float* __restrict__ b1,
    const float* __restrict__ w2, const float* __restrict__ b2,
    float* __restrict__ out) {
  __shared__ float zsh[8];
  __shared__ float acts[2048];
  const int r = blockIdx.x;
  const int t = threadIdx.x;
  if (t < 8) zsh[t] = __cosf(x[(size_t)r * 512 + t]) * __cosf(ry[t]);
  __syncthreads();
  float z[8];
#pragma unroll
  for (int q = 0; q < 8; ++q) z[q] = zsh[q];
#pragma unroll
  for (int i = 0; i < 8; ++i) {
    const int f = t * 8 + i;
    const float* wr = w1 + (size_t)f * 8;
    float4 a = *(const float4*)wr;
    float4 b = *(const float4*)(wr + 4);
    float h = b1[f] + z[0] * a.x + z[1] * a.y + z[2] * a.z + z[3] * a.w +
              z[4] * b.x + z[5] * b.y + z[6] * b.z + z[7] * b.w;
    acts[f] = fmaxf(h, 0.0f);
  }
  __syncthreads();
  for (int ee = 0; ee < 2; ++ee) {
    const int e = t + ee * 256;
    const float* wr = w2 + (size_t)e * 2048;
    float acc = b2[e];
    for (int f = 0; f < 2048; f += 4) {
      float4 wv = *(const float4*)(wr + f);
      float4 av = *(const float4*)(acts + f);
      acc += av.x * wv.x + av.y * wv.y + av.z * wv.z + av.w * wv.w;
    }
    out[(size_t)r * 512 + e] = acc;
  }
}

extern "C" void kernel_launch(void* const* d_in, const int* in_sizes, int n_in,
                              void* d_out, int out_size, void* d_ws,
                              size_t ws_size, hipStream_t stream) {
  const float* x  = (const float*)d_in[0];
  const float* ry = (const float*)d_in[1];
  const float* w1 = (const float*)d_in[2];
  const float* b1 = (const float*)d_in[3];
  const float* w2 = (const float*)d_in[4];
  const float* b2 = (const float*)d_in[5];
  float* out = (float*)d_out;

  const size_t w2b_bytes = (size_t)512 * 2048 * 2;  // 2 MB bf16 w2 image
  if (ws_size < w2b_bytes) {
    k_naive<<<dim3(16384), dim3(256), 0, stream>>>(x, ry, w1, b1, w2, b2, out);
    return;
  }
  unsigned short* w2b = (unsigned short*)d_ws;
  k_w2<<<dim3(512), dim3(256), 0, stream>>>(w2, w2b);
  k_fused<<<dim3(512), dim3(256), 0, stream>>>(x, ry, w1, b1, w2b, b2, out);
}